// Round 10
// baseline (748.302 us; speedup 1.0000x reference)
//
#include <hip/hip_runtime.h>

// SimpleRNN: x(256,2048,8) f32, h(1,256,128), W_ih(128,8), W_hh(128,128),
// b_ih(128), b_hh(128), W_head(1,128), b_head(1)
// out = [pred(256) | last_step_features(256,128) | h_n(256,128)]  (f32)
//
// R8 = R3's exact f32 structure/math (passed, absmax 9.8e-4) + two changes:
//  (a) all weight FMAs are inline-asm v_fmac_f32 with "v" operands ->
//      weights are ASM-CONSUMED at every use => register-resident
//      (R6/R7 proved consumption forces residency: VGPR 80/44 no-spill,
//       while R1/R3's empty-asm pin failed: VGPR stayed 32/40 = per-step
//       L2 re-fetch of W_hh, ~200cy hidden in every one of 2048 steps).
//  (b) in-loop __syncthreads() -> raw s_barrier with lgkmcnt(0) ONLY
//      (no vmcnt drain: x-prefetch + any residual global traffic float
//       across barriers; correctness-safe per R5/R6).
// 256 blocks x 512 threads (8 waves, 2/SIMD). lane = 4*jg + kc; j = 16w+jg.
// Per step: 8 conflict-free broadcast ds_read_b128 of f32 h, 34 fmac,
// DPP quad-reduce (no LDS round-trip), tanh, ping-pong h write, 1 barrier.

#define BB 256
#define TT 2048
#define II 8
#define HH 128
#define THREADS 512

__device__ __forceinline__ float quad_sum(float x) {
    // butterfly over each aligned group of 4 lanes via DPP quad_perm
    int xi = __builtin_bit_cast(int, x);
    int y1 = __builtin_amdgcn_update_dpp(0, xi, 0xB1, 0xF, 0xF, true); // [1,0,3,2]
    float s1 = x + __builtin_bit_cast(float, y1);
    int s1i = __builtin_bit_cast(int, s1);
    int y2 = __builtin_amdgcn_update_dpp(0, s1i, 0x4E, 0xF, 0xF, true); // [2,3,0,1]
    return s1 + __builtin_bit_cast(float, y2);
}

// residency-by-consumption: weight operand is an asm input => must be in a
// VGPR at every use; asm results/uses are not rematerializable.
#define FMAC(acc, a, b) \
    asm("v_fmac_f32 %0, %1, %2" : "+v"(acc) : "v"(a), "v"(b))

__launch_bounds__(THREADS, 1)
__global__ void rnn_fmac_kernel(const float* __restrict__ x,
                                const float* __restrict__ h0,
                                const float* __restrict__ W_ih,
                                const float* __restrict__ W_hh,
                                const float* __restrict__ b_ih,
                                const float* __restrict__ b_hh,
                                const float* __restrict__ W_head,
                                const float* __restrict__ b_head,
                                float* __restrict__ out)
{
    __shared__ __align__(16) float h_lds[2][HH];        // ping-pong hidden state
    __shared__ __align__(16) float x_flat[2 * 16 * II]; // 2 x 16-step x stage

    const int b    = blockIdx.x;
    const int tid  = threadIdx.x;
    const int lane = tid & 63;
    const int w    = tid >> 6;        // wave 0..7
    const int jg   = lane >> 2;       // 0..15
    const int kc   = lane & 3;        // 0..3
    const int j    = w * 16 + jg;     // output index 0..127

    // W_hh chunk, ROTATED so the 4 kc groups' simultaneous broadcast reads of
    // h hit disjoint bank quartets: slot i holds m=(i+2kc)&7.
    float4 w4[8];
    {
        const float4* wr4 = (const float4*)(W_hh + (size_t)j * HH + kc * 32);
        #pragma unroll
        for (int i = 0; i < 8; ++i) w4[i] = wr4[(i + 2 * kc) & 7];
    }
    const float2 wi2   = ((const float2*)(W_ih + j * II))[kc];
    const float  biasq = 0.25f * (b_ih[j] + b_hh[j]);

    const float* xg = x + (size_t)b * TT * II;

    if (tid < HH) {
        h_lds[0][tid] = h0[b * HH + tid];
        x_flat[tid]   = xg[tid];          // x for steps 0..15
    }
    __syncthreads();

    float xpre = 0.0f;
    int xoff = 2 * kc;                    // rolling index into x_flat (mod 256)

    for (int tb = 0; tb < TT; tb += 2) {
        #pragma unroll
        for (int half = 0; half < 2; ++half) {
            const int t  = tb + half;
            const int RB = half;          // read buffer (compile-time)

            if (tid < HH) {
                if ((t & 15) == 0) {
                    const int tn = t + 16;
                    xpre = (tn < TT) ? xg[tn * II + tid] : 0.0f;  // coalesced
                }
            }

            // ---- accumulate: bias/4 + 2 x-FMAs + 32 h-FMAs (all asm fmac) ----
            const float2 xv = *(const float2*)&x_flat[xoff];
            float a0 = biasq, a1 = 0.0f, a2 = 0.0f, a3 = 0.0f;
            FMAC(a0, xv.x, wi2.x);
            FMAC(a0, xv.y, wi2.y);
            #pragma unroll
            for (int i = 0; i < 8; i += 4) {
                const int r0 = (i + 0 + 2 * kc) & 7;
                const int r1 = (i + 1 + 2 * kc) & 7;
                const int r2 = (i + 2 + 2 * kc) & 7;
                const int r3 = (i + 3 + 2 * kc) & 7;
                float4 hv;
                hv = *(const float4*)&h_lds[RB][kc * 32 + r0 * 4];
                FMAC(a0, hv.x, w4[i+0].x); FMAC(a0, hv.y, w4[i+0].y);
                FMAC(a0, hv.z, w4[i+0].z); FMAC(a0, hv.w, w4[i+0].w);
                hv = *(const float4*)&h_lds[RB][kc * 32 + r1 * 4];
                FMAC(a1, hv.x, w4[i+1].x); FMAC(a1, hv.y, w4[i+1].y);
                FMAC(a1, hv.z, w4[i+1].z); FMAC(a1, hv.w, w4[i+1].w);
                hv = *(const float4*)&h_lds[RB][kc * 32 + r2 * 4];
                FMAC(a2, hv.x, w4[i+2].x); FMAC(a2, hv.y, w4[i+2].y);
                FMAC(a2, hv.z, w4[i+2].z); FMAC(a2, hv.w, w4[i+2].w);
                hv = *(const float4*)&h_lds[RB][kc * 32 + r3 * 4];
                FMAC(a3, hv.x, w4[i+3].x); FMAC(a3, hv.y, w4[i+3].y);
                FMAC(a3, hv.z, w4[i+3].z); FMAC(a3, hv.w, w4[i+3].w);
            }
            const float acc = (a0 + a1) + (a2 + a3);

            // cross-lane reduce over the 4 kc lanes (DPP, no barrier)
            const float s = quad_sum(acc);

            // tanh(s) = 1 - 2/(2^(2*log2e*s) + 1)
            const float e2 = __builtin_amdgcn_exp2f(s * 2.8853900817779268f);
            const float hn = 1.0f - 2.0f * __builtin_amdgcn_rcpf(e2 + 1.0f);

            if (kc == 0) h_lds[RB ^ 1][j] = hn;   // 16 distinct banks per wave

            if (tid < HH) {
                if ((t & 15) == 15) x_flat[(((t >> 4) + 1) & 1) * 16 * II + tid] = xpre;
            }

            xoff = (xoff + II) & (2 * 16 * II - 1);
            // ONE barrier per step; lgkmcnt only — no vmcnt drain
            asm volatile("s_waitcnt lgkmcnt(0)\n\ts_barrier" ::: "memory");
        }
    }

    // ---- epilogue: final h is in h_lds[0] (t=2047 wrote RB^1 = 0) ----
    if (tid < HH) {
        const float hl = h_lds[0][tid];
        out[BB + b * HH + tid]           = hl;   // last_step_features
        out[BB + BB * HH + b * HH + tid] = hl;   // h_n
    }
    if (w == 0) {
        float s = h_lds[0][lane]      * W_head[lane]
                + h_lds[0][lane + 64] * W_head[lane + 64];
        #pragma unroll
        for (int off = 32; off > 0; off >>= 1) s += __shfl_down(s, off);
        if (lane == 0) out[b] = s + b_head[0];
    }
}

extern "C" void kernel_launch(void* const* d_in, const int* in_sizes, int n_in,
                              void* d_out, int out_size, void* d_ws, size_t ws_size,
                              hipStream_t stream) {
    const float* x      = (const float*)d_in[0];
    const float* h0     = (const float*)d_in[1];
    const float* W_ih   = (const float*)d_in[2];
    const float* W_hh   = (const float*)d_in[3];
    const float* b_ih   = (const float*)d_in[4];
    const float* b_hh   = (const float*)d_in[5];
    const float* W_head = (const float*)d_in[6];
    const float* b_head = (const float*)d_in[7];
    float* out = (float*)d_out;

    hipLaunchKernelGGL(rnn_fmac_kernel, dim3(BB), dim3(THREADS), 0, stream,
                       x, h0, W_ih, W_hh, b_ih, b_hh, W_head, b_head, out);
}